// Round 1
// baseline (540.494 us; speedup 1.0000x reference)
//
#include <hip/hip_runtime.h>
#include <stdint.h>

// ---------------- problem constants (DSVT-Pillar, Waymo single stage) ----------
// sparse shape 468x468x1; windows 12x12x1 (shift 0,0) and 24x24x1 (shift 6,6)
// set size 36; dim 192; 8 pos-embed heads (4 blocks x 2 shifts)
#define DIM 192
#define SET_SIZE 36

// shift 0: mx=my=40, mz=2 -> id = b*3200 + (x/12)*80 + (y/12)*2 + z ; max id < 6400
#define W0 6400
#define MV0 144
// shift 1: mx=my=21, mz=2 -> id = b*882 + ((x+6)/24)*42 + ((y+6)/24)*2 + z ; max id < 1764
#define W1 1764
#define MV1 576

#define CAP_S0 6144   // worst case sets shift0 ~4709
#define CAP_S1 4096   // worst case sets shift1 ~2467

// ---------------- workspace layout (int units) ----------------
#define OFF_CNT0     0            // 6400
#define OFF_CNT1     6400         // 1764
#define OFF_MOM      8164         // 10 (Sx0,Sy0,Sxx0,Syy0,Sxy0, Sx1,Sy1,Sxx1,Syy1,Sxy1)
#define OFF_S0       8174
#define OFF_S1       8175
#define OFF_ZERO_END 8176
#define OFF_SETBASE0 8192         // 6400
#define OFF_SETBASE1 14592        // 1764
#define OFF_SETWIN0  16356        // 6144
#define OFF_SETWIN1  22500        // 4096
#define OFF_CELL0    26596        // 60000
#define OFF_CELL1    86596        // 60000
#define OFF_SLOTY0   146596       // 6400*144 = 921600
#define OFF_SLOTX0   1068196      // 921600
#define OFF_SLOTY1   1989796      // 1764*576 = 1016064
#define OFF_SLOTX1   3005860      // 1016064
#define OFF_TABLE    4021924      // 8*576*192 floats = 884736
#define WS_TOTAL     4906660      // ints (~18.7 MiB)

// ---------------- kernel 1: per-voxel pass -------------------------------------
// window ids, slot scatter (y-major & x-major), cell ids, integer moments of (xx,yy)
__global__ void voxel_pass(const int* __restrict__ coords, int N, int* __restrict__ ws) {
    int v = blockIdx.x * blockDim.x + threadIdx.x;
    __shared__ int sm[10];
    if (threadIdx.x < 10) sm[threadIdx.x] = 0;
    __syncthreads();
    if (v < N) {
        int b = coords[v * 4 + 0];
        int z = coords[v * 4 + 1];
        int y = coords[v * 4 + 2];
        int x = coords[v * 4 + 3];
        // shift 0
        int xin0 = x % 12, yin0 = y % 12;
        int w0 = b * 3200 + (x / 12) * 80 + (y / 12) * 2 + z;
        atomicAdd(&ws[OFF_CNT0 + w0], 1);
        ws[OFF_SLOTY0 + w0 * MV0 + yin0 * 12 + xin0] = v;
        ws[OFF_SLOTX0 + w0 * MV0 + xin0 * 12 + yin0] = v;
        ws[OFF_CELL0 + v] = yin0 * 12 + xin0;
        // shift 1
        int sx = x + 6, sy = y + 6;
        int xin1 = sx % 24, yin1 = sy % 24;
        int w1 = b * 882 + (sx / 24) * 42 + (sy / 24) * 2 + z;
        atomicAdd(&ws[OFF_CNT1 + w1], 1);
        ws[OFF_SLOTY1 + w1 * MV1 + yin1 * 24 + xin1] = v;
        ws[OFF_SLOTX1 + w1 * MV1 + xin1 * 24 + yin1] = v;
        ws[OFF_CELL1 + v] = yin1 * 24 + xin1;
        // integer moments (pos-embed BN stats; win_x/2 = 6 from base window for BOTH shifts)
        int xx0 = xin0 - 6, yy0 = yin0 - 6;
        int xx1 = xin1 - 6, yy1 = yin1 - 6;
        atomicAdd(&sm[0], xx0); atomicAdd(&sm[1], yy0);
        atomicAdd(&sm[2], xx0 * xx0); atomicAdd(&sm[3], yy0 * yy0); atomicAdd(&sm[4], xx0 * yy0);
        atomicAdd(&sm[5], xx1); atomicAdd(&sm[6], yy1);
        atomicAdd(&sm[7], xx1 * xx1); atomicAdd(&sm[8], yy1 * yy1); atomicAdd(&sm[9], xx1 * yy1);
    }
    __syncthreads();
    if (threadIdx.x < 10) atomicAdd(&ws[OFF_MOM + threadIdx.x], sm[threadIdx.x]);
}

// ---------------- kernel 2: single-block scan over dense window ids ------------
// setnum = ceil(cnt/36); exclusive scan -> setBase; emit setWin (window per set); S total
__global__ void scan_sets(const int* __restrict__ cnt, int W,
                          int* __restrict__ setBase, int* __restrict__ setWin,
                          int* __restrict__ S_out, int cap) {
    __shared__ int sm[256];
    int tid = threadIdx.x;
    int chunk = (W + 255) >> 8;
    int lo = tid * chunk;
    int hi = lo + chunk; if (hi > W) hi = W; if (lo > W) lo = W;
    int local = 0;
    for (int w = lo; w < hi; w++) local += (cnt[w] + SET_SIZE - 1) / SET_SIZE;
    sm[tid] = local;
    __syncthreads();
    for (int off = 1; off < 256; off <<= 1) {
        int t = (tid >= off) ? sm[tid - off] : 0;
        __syncthreads();
        sm[tid] += t;
        __syncthreads();
    }
    int base = sm[tid] - local;   // exclusive prefix
    if (tid == 255) {
        int S = sm[255];
        if (S > cap) S = cap;     // safety clamp (should never trigger)
        *S_out = S;
    }
    for (int w = lo; w < hi; w++) {
        setBase[w] = base;
        int sn = (cnt[w] + SET_SIZE - 1) / SET_SIZE;
        for (int s = 0; s < sn; s++) {
            int idx = base + s;
            if (idx < cap) setWin[idx] = w;
        }
        base += sn;
    }
}

// ---------------- kernel 3: in-place compaction of occupied slots --------------
// one wave (64 threads) per window; ballot prefix; writes land at index <= read index
__global__ void compact_windows(int* __restrict__ slotY, int* __restrict__ slotX, int MV) {
    int w = blockIdx.x;
    int lane = threadIdx.x;
    for (int pass = 0; pass < 2; pass++) {
        int* slot = pass ? slotX : slotY;
        int base = 0;
        for (int p0 = 0; p0 < MV; p0 += 64) {
            int p = p0 + lane;
            int v = (p < MV) ? slot[(size_t)w * MV + p] : -1;
            bool occ = v >= 0;
            unsigned long long m = __ballot(occ);
            int rank = __popcll(m & ((1ull << lane) - 1ull));
            if (occ) slot[(size_t)w * MV + base + rank] = v;
            base += __popcll(m);
        }
    }
}

// ---------------- kernel 4: emit set_voxel_inds + mask -------------------------
// thread per (branch, set, j); runtime S read from ws; outputs as float32
__global__ void write_sets(const int* __restrict__ S_ptr, const int* __restrict__ setWin,
                           const int* __restrict__ setBase, const int* __restrict__ cnt,
                           const int* __restrict__ sortedY, const int* __restrict__ sortedX,
                           int MV, int cap, float* __restrict__ outArea,
                           const int* __restrict__ S_prev /* null for shift0 */) {
    long long tid = (long long)blockIdx.x * blockDim.x + threadIdx.x;
    int S = *S_ptr;
    int j = (int)(tid % SET_SIZE);
    long long t = tid / SET_SIZE;
    int q = (int)(t % cap);
    int branch = (int)(t / cap);
    if (branch >= 2 || q >= S) return;
    long long sOff = 0;
    if (S_prev) sOff = 4LL * SET_SIZE * (long long)(*S_prev);
    int w = setWin[q];
    int i = q - setBase[w];
    int vnum = cnt[w];
    int setnum = (vnum + SET_SIZE - 1) / SET_SIZE;
    int den = setnum * SET_SIZE;
    int r  = ((i * SET_SIZE + j) * vnum) / den;
    int rp = (j > 0) ? (((i * SET_SIZE + j - 1) * vnum) / den) : -1;
    const int* sorted = branch ? sortedX : sortedY;
    int vox = sorted[(size_t)w * MV + r];
    long long idx = (long long)branch * S * SET_SIZE + (long long)q * SET_SIZE + j;
    outArea[sOff + idx] = (float)vox;                               // set_inds
    outArea[sOff + 2LL * S * SET_SIZE + idx] = (r == rp) ? 1.0f : 0.0f;  // mask
}

// ---------------- kernel 5: build pos-embed lookup table -----------------------
// pos_embeds depend only on (k, cell); BN stats closed-form from integer moments.
// h - mu = (xx-mx)*w1[0] + (yy-my)*w1[1]  (b1 cancels); var analytic from moments.
__global__ void build_table(const float* __restrict__ w1, const float* __restrict__ gamma,
                            const float* __restrict__ beta, const float* __restrict__ w2,
                            const float* __restrict__ b2, const int* __restrict__ mom,
                            float* __restrict__ table, int N) {
    int k = blockIdx.x / MV1;          // 0..7
    int cell = blockIdx.x % MV1;       // 0..575
    int shift = k & 1;
    int wdim = shift ? 24 : 12;
    if (cell >= wdim * wdim) return;
    int j = threadIdx.x;               // 0..191
    const int* m = mom + shift * 5;
    double invN = 1.0 / (double)N;
    double mx = m[0] * invN, my = m[1] * invN;
    double vx = m[2] * invN - mx * mx;
    double vy = m[3] * invN - my * my;
    double cxy = m[4] * invN - mx * my;
    int cy = cell / wdim, cx = cell % wdim;
    double xx = (double)(cx - 6), yy = (double)(cy - 6);
    float w10 = w1[(k * 2 + 0) * DIM + j];
    float w11 = w1[(k * 2 + 1) * DIM + j];
    double var = (double)w10 * w10 * vx + (double)w11 * w11 * vy + 2.0 * (double)w10 * w11 * cxy;
    double rs = 1.0 / sqrt(var + 1e-5);
    double hn = ((xx - mx) * (double)w10 + (yy - my) * (double)w11) * rs * (double)gamma[k * DIM + j]
                + (double)beta[k * DIM + j];
    float hr = hn > 0.0 ? (float)hn : 0.0f;
    __shared__ float sh[DIM];
    sh[j] = hr;
    __syncthreads();
    float acc = b2[k * DIM + j];
    const float* w2k = w2 + (size_t)k * DIM * DIM;
    #pragma unroll 8
    for (int i = 0; i < DIM; i++) acc += sh[i] * w2k[i * DIM + j];
    table[((size_t)k * MV1 + cell) * DIM + j] = acc;
}

// ---------------- kernel 6: scatter pos_embeds (float4, coalesced) -------------
__global__ void scatter_pe(const float4* __restrict__ table, const int* __restrict__ cell0,
                           const int* __restrict__ cell1, float4* __restrict__ out, int N) {
    long long tid = (long long)blockIdx.x * blockDim.x + threadIdx.x;
    long long total = 8LL * N * (DIM / 4);
    if (tid >= total) return;
    int q = (int)(tid % (DIM / 4));
    long long t = tid / (DIM / 4);
    int v = (int)(t % N);
    int k = (int)(t / N);
    int cell = (k & 1) ? cell1[v] : cell0[v];
    out[tid] = table[((size_t)k * MV1 + cell) * (DIM / 4) + q];
}

// ---------------- kernel 7: coords int -> float --------------------------------
__global__ void coords_to_float(const int* __restrict__ c, float* __restrict__ o, int n) {
    int i = blockIdx.x * blockDim.x + threadIdx.x;
    if (i < n) o[i] = (float)c[i];
}

extern "C" void kernel_launch(void* const* d_in, const int* in_sizes, int n_in,
                              void* d_out, int out_size, void* d_ws, size_t ws_size,
                              hipStream_t stream) {
    const float* feat  = (const float*)d_in[0];
    const int* coords  = (const int*)d_in[1];
    const float* w1    = (const float*)d_in[2];
    // d_in[3] = pe_b1: cancels inside BN (h - mu), unused
    const float* gamma = (const float*)d_in[4];
    const float* beta  = (const float*)d_in[5];
    const float* w2    = (const float*)d_in[6];
    const float* b2    = (const float*)d_in[7];
    int N = in_sizes[1] / 4;   // 60000
    int* ws = (int*)d_ws;
    float* out = (float*)d_out;

    // init workspace (ws is poisoned 0xAA before every launch)
    hipMemsetAsync(ws, 0, (size_t)OFF_ZERO_END * sizeof(int), stream);
    hipMemsetAsync(ws + OFF_SLOTY0, 0xFF, (size_t)(OFF_TABLE - OFF_SLOTY0) * sizeof(int), stream);

    voxel_pass<<<(N + 255) / 256, 256, 0, stream>>>(coords, N, ws);

    scan_sets<<<1, 256, 0, stream>>>(ws + OFF_CNT0, W0, ws + OFF_SETBASE0, ws + OFF_SETWIN0,
                                     ws + OFF_S0, CAP_S0);
    scan_sets<<<1, 256, 0, stream>>>(ws + OFF_CNT1, W1, ws + OFF_SETBASE1, ws + OFF_SETWIN1,
                                     ws + OFF_S1, CAP_S1);

    compact_windows<<<W0, 64, 0, stream>>>(ws + OFF_SLOTY0, ws + OFF_SLOTX0, MV0);
    compact_windows<<<W1, 64, 0, stream>>>(ws + OFF_SLOTY1, ws + OFF_SLOTX1, MV1);

    // output layout (floats): [feat N*192][coords N*4][inds0 2*S0*36][mask0 2*S0*36]
    //                         [inds1 2*S1*36][mask1 2*S1*36][pos_embeds 8*N*192]
    long long off2 = (long long)N * DIM + (long long)N * 4;
    {
        long long threads = 2LL * CAP_S0 * SET_SIZE;
        write_sets<<<(int)((threads + 255) / 256), 256, 0, stream>>>(
            ws + OFF_S0, ws + OFF_SETWIN0, ws + OFF_SETBASE0, ws + OFF_CNT0,
            ws + OFF_SLOTY0, ws + OFF_SLOTX0, MV0, CAP_S0, out + off2, nullptr);
    }
    {
        long long threads = 2LL * CAP_S1 * SET_SIZE;
        write_sets<<<(int)((threads + 255) / 256), 256, 0, stream>>>(
            ws + OFF_S1, ws + OFF_SETWIN1, ws + OFF_SETBASE1, ws + OFF_CNT1,
            ws + OFF_SLOTY1, ws + OFF_SLOTX1, MV1, CAP_S1, out + off2, ws + OFF_S0);
    }

    build_table<<<8 * MV1, DIM, 0, stream>>>(w1, gamma, beta, w2, b2,
                                             ws + OFF_MOM, (float*)(ws + OFF_TABLE), N);

    long long off6 = (long long)out_size - 8LL * N * DIM;
    {
        long long t4 = 8LL * N * (DIM / 4);
        scatter_pe<<<(int)((t4 + 255) / 256), 256, 0, stream>>>(
            (const float4*)(ws + OFF_TABLE), ws + OFF_CELL0, ws + OFF_CELL1,
            (float4*)(out + off6), N);
    }

    coords_to_float<<<(N * 4 + 255) / 256, 256, 0, stream>>>(coords, out + (long long)N * DIM, N * 4);
    hipMemcpyAsync(out, feat, (size_t)N * DIM * sizeof(float), hipMemcpyDeviceToDevice, stream);
}